// Round 3
// baseline (783.916 us; speedup 1.0000x reference)
//
#include <hip/hip_runtime.h>
#include <math.h>

#define B_SZ   2048
#define F_SZ   12288
#define D_SZ   512
#define N_LK   100000
#define N_PAD  100096
#define NT_STEPS 16   // K=512 / BK=32 for the big GEMM

typedef __attribute__((ext_vector_type(8))) short bf16x8;
typedef __attribute__((ext_vector_type(8))) unsigned short ushort8;
typedef __attribute__((ext_vector_type(4))) float f32x4;

__device__ __forceinline__ unsigned short f2bf(float f) {
  union { float f; unsigned u; } v; v.f = f;
  unsigned r = v.u + 0x7FFFu + ((v.u >> 16) & 1u);
  return (unsigned short)(r >> 16);
}
__device__ __forceinline__ float bf2f(unsigned short h) {
  union { unsigned u; float f; } v; v.u = ((unsigned)h) << 16;
  return v.f;
}

#define GLOAD16(gp, lp) __builtin_amdgcn_global_load_lds( \
    (__attribute__((address_space(1))) void*)(gp),        \
    (__attribute__((address_space(3))) void*)(lp), 16, 0, 0)

#define VMCNT(n) asm volatile("s_waitcnt vmcnt(" #n ")" ::: "memory")

// ---------------- fused x->bf16 conversion + mse partials ----------------

__global__ __launch_bounds__(256) void conv_mse_k(const float* __restrict__ x,
                                                  const float* __restrict__ y,
                                                  unsigned short* __restrict__ xb,
                                                  float* __restrict__ part, long n8) {
  long i = (long)blockIdx.x * 256 + threadIdx.x;
  long stride = (long)gridDim.x * 256;
  float s = 0.f;
  for (; i < n8; i += stride) {
    const float4* px = (const float4*)(x + i * 8);
    const float4* py = (const float4*)(y + i * 8);
    float4 a = px[0], b = px[1];
    float4 c = py[0], d = py[1];
    ushort8 o;
    o[0] = f2bf(a.x); o[1] = f2bf(a.y); o[2] = f2bf(a.z); o[3] = f2bf(a.w);
    o[4] = f2bf(b.x); o[5] = f2bf(b.y); o[6] = f2bf(b.z); o[7] = f2bf(b.w);
    *(ushort8*)(xb + i * 8) = o;
    float t0 = a.x - c.x, t1 = a.y - c.y, t2 = a.z - c.z, t3 = a.w - c.w;
    float t4 = b.x - d.x, t5 = b.y - d.y, t6 = b.z - d.z, t7 = b.w - d.w;
    s += t0 * t0 + t1 * t1 + t2 * t2 + t3 * t3;
    s += t4 * t4 + t5 * t5 + t6 * t6 + t7 * t7;
  }
#pragma unroll
  for (int off = 1; off < 64; off <<= 1) s += __shfl_xor(s, off);
  __shared__ float sm[4];
  if ((threadIdx.x & 63) == 0) sm[threadIdx.x >> 6] = s;
  __syncthreads();
  if (threadIdx.x == 0) part[blockIdx.x] = sm[0] + sm[1] + sm[2] + sm[3];
}

// W [F,D] f32 -> Wt [D,F] bf16
__global__ __launch_bounds__(256) void transpose_w_k(const float* __restrict__ W,
                                                     unsigned short* __restrict__ Wt) {
  __shared__ float tl[64][65];
  int t = threadIdx.x;
  int r0 = blockIdx.x * 64;  // F dim
  int c0 = blockIdx.y * 64;  // D dim
#pragma unroll
  for (int p = 0; p < 16; ++p) {
    int idx = p * 256 + t;
    int r = idx >> 6, c = idx & 63;
    tl[c][r] = W[(size_t)(r0 + r) * D_SZ + c0 + c];
  }
  __syncthreads();
#pragma unroll
  for (int p = 0; p < 2; ++p) {
    int chunk = p * 256 + t;
    int rr = chunk >> 3, cc = (chunk & 7) * 8;
    ushort8 o;
#pragma unroll
    for (int j = 0; j < 8; ++j) o[j] = f2bf(tl[rr][cc + j]);
    *(ushort8*)&Wt[(size_t)(c0 + rr) * F_SZ + r0 + cc] = o;
  }
}

// lookup f32 [N,512] -> bf16 rows (padded to N_PAD) + per-row sum of squares
__global__ __launch_bounds__(256) void conv_lookup_k(const float* __restrict__ lk,
                                                     unsigned short* __restrict__ lb,
                                                     float* __restrict__ lsq) {
  int n = blockIdx.x * 4 + (threadIdx.x >> 6);
  int t = threadIdx.x & 63;
  ushort8 o;
  float s = 0.f;
  if (n < N_LK) {
    const float4* row = (const float4*)(lk + (size_t)n * D_SZ);
    float4 a = row[t * 2], b = row[t * 2 + 1];
    float v[8] = {a.x, a.y, a.z, a.w, b.x, b.y, b.z, b.w};
#pragma unroll
    for (int j = 0; j < 8; ++j) {
      o[j] = f2bf(v[j]);
      float q = bf2f(o[j]);
      s += q * q;
    }
  } else {
#pragma unroll
    for (int j = 0; j < 8; ++j) o[j] = 0;
  }
  *(ushort8*)&lb[(size_t)n * D_SZ + t * 8] = o;
#pragma unroll
  for (int off = 1; off < 64; off <<= 1) s += __shfl_xor(s, off);
  if (t == 0) lsq[n] = (n < N_LK) ? s : 1e30f;
}

__global__ __launch_bounds__(256) void esq_k(const unsigned short* __restrict__ emb,
                                             float* __restrict__ esq) {
  int r = blockIdx.x * 4 + (threadIdx.x >> 6);
  int t = threadIdx.x & 63;
  ushort8 v = *(const ushort8*)&emb[(size_t)r * D_SZ + t * 8];
  float s = 0.f;
#pragma unroll
  for (int j = 0; j < 8; ++j) { float q = bf2f(v[j]); s += q * q; }
#pragma unroll
  for (int off = 1; off < 64; off <<= 1) s += __shfl_xor(s, off);
  if (t == 0) esq[r] = s;
}

__global__ void init_minb_k(unsigned* __restrict__ minb) {
  int i = blockIdx.x * blockDim.x + threadIdx.x;
  if (i < B_SZ) minb[i] = 0x7F800000u;  // +inf
}

// ---------------- GEMM-A (emb = x @ W), m97-style 128x128, store bf16 ----------------
__global__ __launch_bounds__(256) void gemm_a_k(const unsigned short* __restrict__ A,
                                                const unsigned short* __restrict__ Bm,
                                                int M, int N, int K, int mtiles,
                                                unsigned short* __restrict__ Cbf) {
  __shared__ unsigned short lsA[128 * 32];
  __shared__ unsigned short lsB[128 * 32];
  const int tid = threadIdx.x;
  const int bid = blockIdx.x;
  const int mt = bid % mtiles, nt = bid / mtiles;
  const int m0 = mt * 128, n0 = nt * 128;
  const int l = tid & 63;
  const int w = tid >> 6;
  const int wr = (w >> 1) * 64, wc = (w & 1) * 64;
  const int g = l >> 4, lane16 = l & 15;

  const int srow = tid >> 2;
  const int scol = (tid & 3) * 8;
  const unsigned short* Ag0 = A + (size_t)(m0 + srow) * K + scol;
  const unsigned short* Ag1 = A + (size_t)(m0 + 64 + srow) * K + scol;
  const unsigned short* Bg0 = Bm + (size_t)(n0 + srow) * K + scol;
  const unsigned short* Bg1 = Bm + (size_t)(n0 + 64 + srow) * K + scol;
  unsigned short* la0 = &lsA[tid * 8];
  unsigned short* la1 = &lsA[2048 + tid * 8];
  unsigned short* lb0 = &lsB[tid * 8];
  unsigned short* lb1 = &lsB[2048 + tid * 8];

  int ar[4], br[4];
#pragma unroll
  for (int m = 0; m < 4; ++m) ar[m] = (wr + m * 16 + lane16) * 32 + g * 8;
#pragma unroll
  for (int n = 0; n < 4; ++n) br[n] = (wc + n * 16 + lane16) * 32 + g * 8;

  f32x4 acc[4][4] = {};

  for (int k0 = 0; k0 < K; k0 += 32) {
    GLOAD16(Ag0 + k0, la0);
    GLOAD16(Ag1 + k0, la1);
    GLOAD16(Bg0 + k0, lb0);
    GLOAD16(Bg1 + k0, lb1);
    __syncthreads();
    bf16x8 af[4], bfv[4];
#pragma unroll
    for (int m = 0; m < 4; ++m) af[m] = *(const bf16x8*)&lsA[ar[m]];
#pragma unroll
    for (int n = 0; n < 4; ++n) bfv[n] = *(const bf16x8*)&lsB[br[n]];
#pragma unroll
    for (int m = 0; m < 4; ++m)
#pragma unroll
      for (int n = 0; n < 4; ++n)
        acc[m][n] = __builtin_amdgcn_mfma_f32_16x16x32_bf16(af[m], bfv[n], acc[m][n], 0, 0, 0);
    __syncthreads();
  }
#pragma unroll
  for (int m = 0; m < 4; ++m)
#pragma unroll
    for (int n = 0; n < 4; ++n)
#pragma unroll
      for (int r = 0; r < 4; ++r) {
        int row = m0 + wr + m * 16 + g * 4 + r;
        int col = n0 + wc + n * 16 + lane16;
        Cbf[(size_t)row * N + col] = f2bf(acc[m][n][r]);
      }
}

// ---------------- GEMM-B: fused cdist-min, 256x256 tile, BK=32, 4-deep ring ----------------
// 8 waves (2M x 4N), each wave owns 128x64 of C. LDS: 4 buffers x (A 16KB + B 16KB) = 128KB.
// Ring invariant at top of step t: buf[t&3] visible (vmcnt'd + barrier'd);
// tiles t+1, t+2 outstanding; buf[(t+3)&3] free (its tile t-1 reads finished at the
// barrier that opened step t). Each step = 2 fine phases (m201-style):
//   phase A: read bfv[0..3],af[0..3] | issue A-half stage(t+3) | bar | lgkm0 | 16 MFMA | bar
//   phase B: read af[4..7]           | issue B-half stage(t+3) | vmcnt(8) retire t+1 | bar
//            | lgkm0 | 16 MFMA | bar
// vmcnt(8): outstanding <= {t+1:4, t+2:4, t+3:4}; loads retire in issue order, all
// threads issue identical load sequences -> counted wait + barrier is race-free.
__global__ __launch_bounds__(512, 2) void gemm_min_k(
    const unsigned short* __restrict__ A,   // emb [2048][512] bf16
    const unsigned short* __restrict__ Bm,  // lb  [100096][512] bf16
    const float* __restrict__ esq, const float* __restrict__ lsq,
    unsigned* __restrict__ minb) {
  __shared__ unsigned short lsA[4 * 8192];
  __shared__ unsigned short lsB[4 * 8192];

  const int tid = threadIdx.x;
  // bijective XCD swizzle: grid 3128 = 8 * 391; consecutive wg (same XCD) share nt
  const int wg = (blockIdx.x & 7) * 391 + (blockIdx.x >> 3);
  const int mt = wg & 7;        // 8 M-tiles
  const int nt = wg >> 3;       // 391 N-tiles
  const int m0 = mt * 256, n0 = nt * 256;

  const int l = tid & 63;
  const int wid = tid >> 6;
  const int wm = wid >> 2;      // 0..1 -> rows wm*128
  const int wn = wid & 3;       // 0..3 -> cols wn*64
  const int g = l >> 4, lane16 = l & 15;

  // staging: linear LDS dest (global_load_lds requirement); global source column slot
  // pre-swizzled so ds_read's slot' = slot ^ ((row>>1)&3) finds the right data.
  const int srow = tid >> 2;                         // 0..127
  const int sslot = (tid & 3) ^ ((tid >> 3) & 3);    // == (tid&3) ^ ((row>>1)&3)
  const unsigned short* Ag0 = A + (size_t)(m0 + srow) * D_SZ + sslot * 8;
  const unsigned short* Ag1 = A + (size_t)(m0 + 128 + srow) * D_SZ + sslot * 8;
  const unsigned short* Bg0 = Bm + (size_t)(n0 + srow) * D_SZ + sslot * 8;
  const unsigned short* Bg1 = Bm + (size_t)(n0 + 128 + srow) * D_SZ + sslot * 8;

  // fragment ds_read element offsets (swizzled)
  int ar[8], br[4];
#pragma unroll
  for (int m = 0; m < 8; ++m) {
    int row = wm * 128 + m * 16 + lane16;
    ar[m] = row * 32 + ((g ^ ((row >> 1) & 3)) * 8);
  }
#pragma unroll
  for (int n = 0; n < 4; ++n) {
    int row = wn * 64 + n * 16 + lane16;
    br[n] = row * 32 + ((g ^ ((row >> 1) & 3)) * 8);
  }

  f32x4 acc[8][4] = {};

#define GSTEP(T, DOSTAGE, VMA)                                                 \
  do {                                                                         \
    const int b_ = (T) & 3;                                                    \
    const unsigned short* pA_ = &lsA[b_ * 8192];                               \
    const unsigned short* pB_ = &lsB[b_ * 8192];                               \
    bf16x8 bfv_[4], af_[4];                                                    \
    _Pragma("unroll")                                                          \
    for (int n_ = 0; n_ < 4; ++n_) bfv_[n_] = *(const bf16x8*)&pB_[br[n_]];    \
    _Pragma("unroll")                                                          \
    for (int m_ = 0; m_ < 4; ++m_) af_[m_] = *(const bf16x8*)&pA_[ar[m_]];     \
    if (DOSTAGE) {                                                             \
      const int kt_ = (T) + 3, bn_ = kt_ & 3;                                  \
      GLOAD16(Ag0 + kt_ * 32, &lsA[bn_ * 8192 + tid * 8]);                     \
      GLOAD16(Ag1 + kt_ * 32, &lsA[bn_ * 8192 + 4096 + tid * 8]);              \
    }                                                                          \
    __builtin_amdgcn_s_barrier();                                              \
    asm volatile("s_waitcnt lgkmcnt(0)" ::: "memory");                         \
    __builtin_amdgcn_sched_barrier(0);                                         \
    __builtin_amdgcn_s_setprio(1);                                             \
    _Pragma("unroll")                                                          \
    for (int m_ = 0; m_ < 4; ++m_)                                             \
      _Pragma("unroll")                                                        \
      for (int n_ = 0; n_ < 4; ++n_)                                           \
        acc[m_][n_] = __builtin_amdgcn_mfma_f32_16x16x32_bf16(                 \
            af_[m_], bfv_[n_], acc[m_][n_], 0, 0, 0);                          \
    __builtin_amdgcn_s_setprio(0);                                             \
    __builtin_amdgcn_s_barrier();                                              \
    _Pragma("unroll")                                                          \
    for (int m_ = 0; m_ < 4; ++m_) af_[m_] = *(const bf16x8*)&pA_[ar[m_ + 4]]; \
    if (DOSTAGE) {                                                             \
      const int kt_ = (T) + 3, bn_ = kt_ & 3;                                  \
      GLOAD16(Bg0 + kt_ * 32, &lsB[bn_ * 8192 + tid * 8]);                     \
      GLOAD16(Bg1 + kt_ * 32, &lsB[bn_ * 8192 + 4096 + tid * 8]);              \
    }                                                                          \
    VMA;                                                                       \
    __builtin_amdgcn_s_barrier();                                              \
    asm volatile("s_waitcnt lgkmcnt(0)" ::: "memory");                         \
    __builtin_amdgcn_sched_barrier(0);                                         \
    __builtin_amdgcn_s_setprio(1);                                             \
    _Pragma("unroll")                                                          \
    for (int m_ = 0; m_ < 4; ++m_)                                             \
      _Pragma("unroll")                                                        \
      for (int n_ = 0; n_ < 4; ++n_)                                           \
        acc[m_ + 4][n_] = __builtin_amdgcn_mfma_f32_16x16x32_bf16(             \
            af_[m_], bfv_[n_], acc[m_ + 4][n_], 0, 0, 0);                      \
    __builtin_amdgcn_s_setprio(0);                                             \
    __builtin_amdgcn_s_barrier();                                              \
  } while (0)

  // prologue: stage tiles 0,1,2 (12 loads in flight), retire tile 0
  {
    const int kts[3] = {0, 1, 2};
#pragma unroll
    for (int i = 0; i < 3; ++i) {
      const int kt_ = kts[i], bn_ = kt_ & 3;
      GLOAD16(Ag0 + kt_ * 32, &lsA[bn_ * 8192 + tid * 8]);
      GLOAD16(Ag1 + kt_ * 32, &lsA[bn_ * 8192 + 4096 + tid * 8]);
      GLOAD16(Bg0 + kt_ * 32, &lsB[bn_ * 8192 + tid * 8]);
      GLOAD16(Bg1 + kt_ * 32, &lsB[bn_ * 8192 + 4096 + tid * 8]);
    }
  }
  VMCNT(8);
  __builtin_amdgcn_s_barrier();

  for (int t = 0; t < NT_STEPS - 3; ++t) {
    GSTEP(t, true, VMCNT(8));       // retire tile t+1; t+2, t+3 stay in flight
  }
  GSTEP(NT_STEPS - 3, false, VMCNT(4));  // retire tile 14; 15 in flight
  GSTEP(NT_STEPS - 2, false, VMCNT(0));  // drain
  GSTEP(NT_STEPS - 1, false, (void)0);
#undef GSTEP

  // epilogue: per-row min over this block's 256 cols -> atomicMin
  float lsql[4];
#pragma unroll
  for (int n = 0; n < 4; ++n) lsql[n] = lsq[n0 + wn * 64 + n * 16 + lane16];
#pragma unroll
  for (int m = 0; m < 8; ++m) {
#pragma unroll
    for (int r = 0; r < 4; ++r) {
      float best = fminf(fminf(lsql[0] - 2.0f * acc[m][0][r], lsql[1] - 2.0f * acc[m][1][r]),
                         fminf(lsql[2] - 2.0f * acc[m][2][r], lsql[3] - 2.0f * acc[m][3][r]));
#pragma unroll
      for (int off = 1; off < 16; off <<= 1) best = fminf(best, __shfl_xor(best, off));
      if (lane16 == 0) {
        int row = m0 + wm * 128 + m * 16 + g * 4 + r;
        float val = fmaxf(esq[row] + best, 0.0f);
        atomicMin(&minb[row], __float_as_uint(val));  // nonneg floats order as uints
      }
    }
  }
}

// ---------------- final reductions ----------------

__global__ __launch_bounds__(256) void mse_final_k(const float* __restrict__ part,
                                                   float* __restrict__ msev,
                                                   int nparts, float inv_n) {
  float s = 0.f;
  for (int i = threadIdx.x; i < nparts; i += 256) s += part[i];
#pragma unroll
  for (int off = 1; off < 64; off <<= 1) s += __shfl_xor(s, off);
  __shared__ float sm[4];
  if ((threadIdx.x & 63) == 0) sm[threadIdx.x >> 6] = s;
  __syncthreads();
  if (threadIdx.x == 0) msev[0] = (sm[0] + sm[1] + sm[2] + sm[3]) * inv_n;
}

__global__ void finalize_k(const unsigned* __restrict__ minb,
                           const float* __restrict__ msev,
                           float* __restrict__ out, int n) {
  int i = blockIdx.x * blockDim.x + threadIdx.x;
  if (i < n) {
    float sq = __uint_as_float(minb[i]);
    float d = sqrtf(sq);
    out[i] = msev[0] + fminf(50.0f - d, 0.0f) * 5.0f;
  }
}

// ---------------- launch ----------------

extern "C" void kernel_launch(void* const* d_in, const int* in_sizes, int n_in,
                              void* d_out, int out_size, void* d_ws, size_t ws_size,
                              hipStream_t stream) {
  const float* x  = (const float*)d_in[0];
  const float* y  = (const float*)d_in[1];
  const float* W  = (const float*)d_in[2];
  const float* lk = (const float*)d_in[3];
  float* out = (float*)d_out;

  char* ws = (char*)d_ws;
  size_t off = 0;
  auto alloc = [&](size_t bytes) -> void* {
    void* p = ws + off;
    off = (off + bytes + 255) & ~(size_t)255;
    return p;
  };
  unsigned short* xb  = (unsigned short*)alloc((size_t)B_SZ * F_SZ * 2);
  unsigned short* Wt  = (unsigned short*)alloc((size_t)D_SZ * F_SZ * 2);
  unsigned short* lb  = (unsigned short*)alloc((size_t)N_PAD * D_SZ * 2);
  float* lsq          = (float*)alloc((size_t)N_PAD * 4);
  unsigned short* emb = (unsigned short*)alloc((size_t)B_SZ * D_SZ * 2);
  float* esq          = (float*)alloc((size_t)B_SZ * 4);
  unsigned* minb      = (unsigned*)alloc((size_t)B_SZ * 4);
  float* msep         = (float*)alloc(2048 * 4);
  float* msev         = (float*)alloc(256);
  (void)ws_size; (void)in_sizes; (void)n_in; (void)out_size;

  conv_mse_k<<<2048, 256, 0, stream>>>(x, y, xb, msep, (long)B_SZ * F_SZ / 8);
  dim3 tg(F_SZ / 64, D_SZ / 64);
  transpose_w_k<<<tg, 256, 0, stream>>>(W, Wt);
  conv_lookup_k<<<N_PAD / 4, 256, 0, stream>>>(lk, lb, lsq);
  init_minb_k<<<(B_SZ + 255) / 256, 256, 0, stream>>>(minb);

  // emb = x @ W  (xb [2048,12288] * Wt [512,12288]^T)
  gemm_a_k<<<(B_SZ / 128) * (D_SZ / 128), 256, 0, stream>>>(
      xb, Wt, B_SZ, D_SZ, F_SZ, B_SZ / 128, emb);
  esq_k<<<B_SZ / 4, 256, 0, stream>>>(emb, esq);

  // fused cdist-min: emb [2048,512] * lb [100096,512]^T, 256x256 tiles
  gemm_min_k<<<(B_SZ / 256) * (N_PAD / 256), 512, 0, stream>>>(emb, lb, esq, lsq, minb);

  mse_final_k<<<1, 256, 0, stream>>>(msep, msev, 2048, 1.0f / ((float)B_SZ * (float)F_SZ));
  finalize_k<<<(B_SZ + 255) / 256, 256, 0, stream>>>(minb, msev, out, B_SZ);
}

// Round 4
// 452.044 us; speedup vs baseline: 1.7342x; 1.7342x over previous
//
#include <hip/hip_runtime.h>
#include <math.h>

#define B_SZ   2048
#define F_SZ   12288
#define D_SZ   512
#define N_LK   100000
#define N_PAD  100096
#define NTILES 391          // N_PAD / 256
#define NGRP   32           // persistent groups along nt

typedef __attribute__((ext_vector_type(8))) short bf16x8;
typedef __attribute__((ext_vector_type(8))) unsigned short ushort8;
typedef __attribute__((ext_vector_type(4))) float f32x4;

__device__ __forceinline__ unsigned short f2bf(float f) {
  union { float f; unsigned u; } v; v.f = f;
  unsigned r = v.u + 0x7FFFu + ((v.u >> 16) & 1u);
  return (unsigned short)(r >> 16);
}
__device__ __forceinline__ float bf2f(unsigned short h) {
  union { unsigned u; float f; } v; v.u = ((unsigned)h) << 16;
  return v.f;
}

#define GLOAD16(gp, lp) __builtin_amdgcn_global_load_lds( \
    (__attribute__((address_space(1))) void*)(gp),        \
    (__attribute__((address_space(3))) void*)(lp), 16, 0, 0)

#define VMCNT(n) asm volatile("s_waitcnt vmcnt(" #n ")" ::: "memory")

// ---------------- fused x->bf16 conversion + mse partials ----------------

__global__ __launch_bounds__(256) void conv_mse_k(const float* __restrict__ x,
                                                  const float* __restrict__ y,
                                                  unsigned short* __restrict__ xb,
                                                  float* __restrict__ part, long n8) {
  long i = (long)blockIdx.x * 256 + threadIdx.x;
  long stride = (long)gridDim.x * 256;
  float s = 0.f;
  for (; i < n8; i += stride) {
    const float4* px = (const float4*)(x + i * 8);
    const float4* py = (const float4*)(y + i * 8);
    float4 a = px[0], b = px[1];
    float4 c = py[0], d = py[1];
    ushort8 o;
    o[0] = f2bf(a.x); o[1] = f2bf(a.y); o[2] = f2bf(a.z); o[3] = f2bf(a.w);
    o[4] = f2bf(b.x); o[5] = f2bf(b.y); o[6] = f2bf(b.z); o[7] = f2bf(b.w);
    *(ushort8*)(xb + i * 8) = o;
    float t0 = a.x - c.x, t1 = a.y - c.y, t2 = a.z - c.z, t3 = a.w - c.w;
    float t4 = b.x - d.x, t5 = b.y - d.y, t6 = b.z - d.z, t7 = b.w - d.w;
    s += t0 * t0 + t1 * t1 + t2 * t2 + t3 * t3;
    s += t4 * t4 + t5 * t5 + t6 * t6 + t7 * t7;
  }
#pragma unroll
  for (int off = 1; off < 64; off <<= 1) s += __shfl_xor(s, off);
  __shared__ float sm[4];
  if ((threadIdx.x & 63) == 0) sm[threadIdx.x >> 6] = s;
  __syncthreads();
  if (threadIdx.x == 0) part[blockIdx.x] = sm[0] + sm[1] + sm[2] + sm[3];
}

// W [F,D] f32 -> Wt [D,F] bf16
__global__ __launch_bounds__(256) void transpose_w_k(const float* __restrict__ W,
                                                     unsigned short* __restrict__ Wt) {
  __shared__ float tl[64][65];
  int t = threadIdx.x;
  int r0 = blockIdx.x * 64;  // F dim
  int c0 = blockIdx.y * 64;  // D dim
#pragma unroll
  for (int p = 0; p < 16; ++p) {
    int idx = p * 256 + t;
    int r = idx >> 6, c = idx & 63;
    tl[c][r] = W[(size_t)(r0 + r) * D_SZ + c0 + c];
  }
  __syncthreads();
#pragma unroll
  for (int p = 0; p < 2; ++p) {
    int chunk = p * 256 + t;
    int rr = chunk >> 3, cc = (chunk & 7) * 8;
    ushort8 o;
#pragma unroll
    for (int j = 0; j < 8; ++j) o[j] = f2bf(tl[rr][cc + j]);
    *(ushort8*)&Wt[(size_t)(c0 + rr) * F_SZ + r0 + cc] = o;
  }
}

// lookup f32 [N,512] -> bf16 rows (padded) + per-row sum of squares
__global__ __launch_bounds__(256) void conv_lookup_k(const float* __restrict__ lk,
                                                     unsigned short* __restrict__ lb,
                                                     float* __restrict__ lsq) {
  int n = blockIdx.x * 4 + (threadIdx.x >> 6);
  int t = threadIdx.x & 63;
  ushort8 o;
  float s = 0.f;
  if (n < N_LK) {
    const float4* row = (const float4*)(lk + (size_t)n * D_SZ);
    float4 a = row[t * 2], b = row[t * 2 + 1];
    float v[8] = {a.x, a.y, a.z, a.w, b.x, b.y, b.z, b.w};
#pragma unroll
    for (int j = 0; j < 8; ++j) {
      o[j] = f2bf(v[j]);
      float q = bf2f(o[j]);
      s += q * q;
    }
  } else {
#pragma unroll
    for (int j = 0; j < 8; ++j) o[j] = 0;
  }
  *(ushort8*)&lb[(size_t)n * D_SZ + t * 8] = o;
#pragma unroll
  for (int off = 1; off < 64; off <<= 1) s += __shfl_xor(s, off);
  if (t == 0) lsq[n] = (n < N_LK) ? s : 1e30f;
}

__global__ __launch_bounds__(256) void zero_f32_k(float* __restrict__ p, long n4) {
  long i = (long)blockIdx.x * 256 + threadIdx.x;
  long stride = (long)gridDim.x * 256;
  float4 z = {0.f, 0.f, 0.f, 0.f};
  for (; i < n4; i += stride) ((float4*)p)[i] = z;
}

// ---------------- GEMM-A split-K=4: embf(f32) += xb[128-tile] @ Wt^T[128-tile] ----------------
// grid 256 = mt(16) x dt(4) x ks(4); K-slice 3072 (96 steps). atomicAdd f32 epilogue
// (4 writers/address, no contention; output is hinge-clamped so rounding order is harmless).
__global__ __launch_bounds__(256) void gemm_a_sk(const unsigned short* __restrict__ A,
                                                 const unsigned short* __restrict__ Bm,
                                                 float* __restrict__ embf) {
  __shared__ unsigned short lsA[128 * 32];
  __shared__ unsigned short lsB[128 * 32];
  const int tid = threadIdx.x;
  const int bid = blockIdx.x;
  const int mt = bid & 15, dt = (bid >> 4) & 3, ks = bid >> 6;
  const int m0 = mt * 128, n0 = dt * 128;
  const int k0base = ks * 3072;
  const int l = tid & 63;
  const int w = tid >> 6;
  const int wr = (w >> 1) * 64, wc = (w & 1) * 64;
  const int g = l >> 4, lane16 = l & 15;

  const int srow = tid >> 2;
  const int scol = (tid & 3) * 8;
  const unsigned short* Ag0 = A + (size_t)(m0 + srow) * F_SZ + scol + k0base;
  const unsigned short* Ag1 = A + (size_t)(m0 + 64 + srow) * F_SZ + scol + k0base;
  const unsigned short* Bg0 = Bm + (size_t)(n0 + srow) * F_SZ + scol + k0base;
  const unsigned short* Bg1 = Bm + (size_t)(n0 + 64 + srow) * F_SZ + scol + k0base;
  unsigned short* la0 = &lsA[tid * 8];
  unsigned short* la1 = &lsA[2048 + tid * 8];
  unsigned short* lb0 = &lsB[tid * 8];
  unsigned short* lb1 = &lsB[2048 + tid * 8];

  int ar[4], br[4];
#pragma unroll
  for (int m = 0; m < 4; ++m) ar[m] = (wr + m * 16 + lane16) * 32 + g * 8;
#pragma unroll
  for (int n = 0; n < 4; ++n) br[n] = (wc + n * 16 + lane16) * 32 + g * 8;

  f32x4 acc[4][4] = {};

  for (int k0 = 0; k0 < 3072; k0 += 32) {
    GLOAD16(Ag0 + k0, la0);
    GLOAD16(Ag1 + k0, la1);
    GLOAD16(Bg0 + k0, lb0);
    GLOAD16(Bg1 + k0, lb1);
    __syncthreads();
    bf16x8 af[4], bfv[4];
#pragma unroll
    for (int m = 0; m < 4; ++m) af[m] = *(const bf16x8*)&lsA[ar[m]];
#pragma unroll
    for (int n = 0; n < 4; ++n) bfv[n] = *(const bf16x8*)&lsB[br[n]];
#pragma unroll
    for (int m = 0; m < 4; ++m)
#pragma unroll
      for (int n = 0; n < 4; ++n)
        acc[m][n] = __builtin_amdgcn_mfma_f32_16x16x32_bf16(af[m], bfv[n], acc[m][n], 0, 0, 0);
    __syncthreads();
  }
#pragma unroll
  for (int m = 0; m < 4; ++m)
#pragma unroll
    for (int n = 0; n < 4; ++n)
#pragma unroll
      for (int r = 0; r < 4; ++r) {
        int row = m0 + wr + m * 16 + g * 4 + r;
        int col = n0 + wc + n * 16 + lane16;
        atomicAdd(&embf[(size_t)row * D_SZ + col], acc[m][n][r]);
      }
}

// embf f32 -> emb bf16 + per-row esq (of the bf16-rounded values)
__global__ __launch_bounds__(256) void esq_conv_k(const float* __restrict__ embf,
                                                  unsigned short* __restrict__ emb,
                                                  float* __restrict__ esq) {
  int r = blockIdx.x * 4 + (threadIdx.x >> 6);
  int t = threadIdx.x & 63;
  const float4* row = (const float4*)(embf + (size_t)r * D_SZ);
  float4 a = row[t * 2], b = row[t * 2 + 1];
  float v[8] = {a.x, a.y, a.z, a.w, b.x, b.y, b.z, b.w};
  ushort8 o;
  float s = 0.f;
#pragma unroll
  for (int j = 0; j < 8; ++j) {
    o[j] = f2bf(v[j]);
    float q = bf2f(o[j]);
    s += q * q;
  }
  *(ushort8*)&emb[(size_t)r * D_SZ + t * 8] = o;
#pragma unroll
  for (int off = 1; off < 64; off <<= 1) s += __shfl_xor(s, off);
  if (t == 0) esq[r] = s;
}

// ---------------- GEMM-B: persistent fused cdist-min ----------------
// grid 256 (1 block/CU). mt = bid&7 (same-XCD blocks share the A-panel in L2),
// grp = bid>>3; block handles nt = grp, grp+32, ... (<391), folding per-row min
// in registers across nt. 4-deep LDS ring runs continuously across nt boundaries;
// vmcnt(8) steady (retire tile t+1; t+2,t+3 in flight; loads complete in order and
// all threads issue identical load sequences -> counted wait + barrier race-free).
// No atomics: one non-atomic minpart[grp][row] store per block at the end.
__global__ __launch_bounds__(512, 2) void gemm_min_k(
    const unsigned short* __restrict__ A,   // emb [2048][512] bf16
    const unsigned short* __restrict__ Bm,  // lb  [100096][512] bf16
    const float* __restrict__ esq, const float* __restrict__ lsq,
    float* __restrict__ minpart) {          // [NGRP][2048]
  __shared__ unsigned short lsA[4 * 8192];
  __shared__ unsigned short lsB[4 * 8192];

  const int tid = threadIdx.x;
  const int mt = blockIdx.x & 7;
  const int grp = blockIdx.x >> 3;     // 0..31
  const int m0 = mt * 256;
  const int J = (NTILES - grp + NGRP - 1) / NGRP;  // 12 or 13 nt-tiles
  const int T = J * 16;                            // total K-steps

  const int l = tid & 63;
  const int wid = tid >> 6;
  const int wm = wid >> 2;      // 0..1 -> rows wm*128
  const int wn = wid & 3;       // 0..3 -> cols wn*64
  const int g = l >> 4, lane16 = l & 15;

  // staging: linear LDS dest; global source column slot pre-swizzled so ds_read's
  // slot' = slot ^ ((row>>1)&3) finds the right data (both-sides-or-neither rule).
  const int srow = tid >> 2;                         // 0..127
  const int sslot = (tid & 3) ^ ((tid >> 3) & 3);
  const unsigned short* Ag0 = A + (size_t)(m0 + srow) * D_SZ + sslot * 8;
  const unsigned short* Ag1 = A + (size_t)(m0 + 128 + srow) * D_SZ + sslot * 8;
  const unsigned short* Bgs = Bm + (size_t)srow * D_SZ + sslot * 8;

  int ar[8], br[4];
#pragma unroll
  for (int m = 0; m < 8; ++m) {
    int row = wm * 128 + m * 16 + lane16;
    ar[m] = row * 32 + ((g ^ ((row >> 1) & 3)) * 8);
  }
#pragma unroll
  for (int n = 0; n < 4; ++n) {
    int row = wn * 64 + n * 16 + lane16;
    br[n] = row * 32 + ((g ^ ((row >> 1) & 3)) * 8);
  }

  f32x4 acc[8][4] = {};
  float rmin[8][4];
#pragma unroll
  for (int m = 0; m < 8; ++m)
#pragma unroll
    for (int r = 0; r < 4; ++r) rmin[m][r] = 3.0e38f;

  auto stage = [&](int s) {
    const int kt = (s & 15) * 32;
    const int b = s & 3;
    const size_t nrow = (size_t)(grp + NGRP * (s >> 4)) * 256 * D_SZ;
    GLOAD16(Ag0 + kt, &lsA[b * 8192 + tid * 8]);
    GLOAD16(Ag1 + kt, &lsA[b * 8192 + 4096 + tid * 8]);
    GLOAD16(Bgs + nrow + kt, &lsB[b * 8192 + tid * 8]);
    GLOAD16(Bgs + nrow + (size_t)128 * D_SZ + kt, &lsB[b * 8192 + 4096 + tid * 8]);
  };
  auto step = [&](int b) {
    const unsigned short* pA = &lsA[b * 8192];
    const unsigned short* pB = &lsB[b * 8192];
    bf16x8 af[8], bfv[4];
#pragma unroll
    for (int n = 0; n < 4; ++n) bfv[n] = *(const bf16x8*)&pB[br[n]];
#pragma unroll
    for (int m = 0; m < 8; ++m) af[m] = *(const bf16x8*)&pA[ar[m]];
    __builtin_amdgcn_s_setprio(1);
#pragma unroll
    for (int m = 0; m < 8; ++m)
#pragma unroll
      for (int n = 0; n < 4; ++n)
        acc[m][n] = __builtin_amdgcn_mfma_f32_16x16x32_bf16(af[m], bfv[n], acc[m][n], 0, 0, 0);
    __builtin_amdgcn_s_setprio(0);
  };
  auto fold = [&](int j) {
    const int n0s = (grp + NGRP * j) * 256;
    float lsql[4];
#pragma unroll
    for (int n = 0; n < 4; ++n) lsql[n] = lsq[n0s + wn * 64 + n * 16 + lane16];
#pragma unroll
    for (int m = 0; m < 8; ++m)
#pragma unroll
      for (int r = 0; r < 4; ++r) {
        float v = fminf(fminf(lsql[0] - 2.0f * acc[m][0][r], lsql[1] - 2.0f * acc[m][1][r]),
                        fminf(lsql[2] - 2.0f * acc[m][2][r], lsql[3] - 2.0f * acc[m][3][r]));
        rmin[m][r] = fminf(rmin[m][r], v);
      }
#pragma unroll
    for (int m = 0; m < 8; ++m)
#pragma unroll
      for (int n = 0; n < 4; ++n) acc[m][n] = f32x4{0.f, 0.f, 0.f, 0.f};
  };

  // prologue: 3 tiles in flight, retire tile 0
  stage(0); stage(1); stage(2);
  VMCNT(8);
  __builtin_amdgcn_s_barrier();

  for (int t = 0; t < T - 3; ++t) {
    stage(t + 3);
    step(t & 3);
    if ((t & 15) == 15) fold(t >> 4);   // uniform branch; nt boundary
    VMCNT(8);
    __builtin_amdgcn_s_barrier();
  }
  step((T - 3) & 3);                     // kt 13 of last nt
  VMCNT(4);
  __builtin_amdgcn_s_barrier();
  step((T - 2) & 3);
  VMCNT(0);
  __builtin_amdgcn_s_barrier();
  step((T - 1) & 3);
  fold(J - 1);

  // writeout: reduce rmin over the 16-lane col group, one store per (grp,row)
#pragma unroll
  for (int m = 0; m < 8; ++m)
#pragma unroll
    for (int r = 0; r < 4; ++r) {
      float best = rmin[m][r];
#pragma unroll
      for (int off = 1; off < 16; off <<= 1) best = fminf(best, __shfl_xor(best, off));
      if (lane16 == 0) {
        int row = m0 + wm * 128 + m * 16 + g * 4 + r;
        minpart[grp * B_SZ + row] = fmaxf(esq[row] + best, 0.0f);
      }
    }
}

// ---------------- final reductions ----------------

__global__ __launch_bounds__(256) void mse_final_k(const float* __restrict__ part,
                                                   float* __restrict__ msev,
                                                   int nparts, float inv_n) {
  float s = 0.f;
  for (int i = threadIdx.x; i < nparts; i += 256) s += part[i];
#pragma unroll
  for (int off = 1; off < 64; off <<= 1) s += __shfl_xor(s, off);
  __shared__ float sm[4];
  if ((threadIdx.x & 63) == 0) sm[threadIdx.x >> 6] = s;
  __syncthreads();
  if (threadIdx.x == 0) msev[0] = (sm[0] + sm[1] + sm[2] + sm[3]) * inv_n;
}

__global__ void finalize_k(const float* __restrict__ minpart,
                           const float* __restrict__ msev,
                           float* __restrict__ out, int n) {
  int i = blockIdx.x * blockDim.x + threadIdx.x;
  if (i < n) {
    float m = 3.0e38f;
#pragma unroll
    for (int gp = 0; gp < NGRP; ++gp) m = fminf(m, minpart[gp * B_SZ + i]);
    out[i] = msev[0] + fminf(50.0f - sqrtf(m), 0.0f) * 5.0f;
  }
}

// ---------------- launch ----------------

extern "C" void kernel_launch(void* const* d_in, const int* in_sizes, int n_in,
                              void* d_out, int out_size, void* d_ws, size_t ws_size,
                              hipStream_t stream) {
  const float* x  = (const float*)d_in[0];
  const float* y  = (const float*)d_in[1];
  const float* W  = (const float*)d_in[2];
  const float* lk = (const float*)d_in[3];
  float* out = (float*)d_out;

  char* ws = (char*)d_ws;
  size_t off = 0;
  auto alloc = [&](size_t bytes) -> void* {
    void* p = ws + off;
    off = (off + bytes + 255) & ~(size_t)255;
    return p;
  };
  unsigned short* xb  = (unsigned short*)alloc((size_t)B_SZ * F_SZ * 2);   // 50.3 MB
  unsigned short* Wt  = (unsigned short*)alloc((size_t)D_SZ * F_SZ * 2);   // 12.6 MB
  unsigned short* lb  = (unsigned short*)alloc((size_t)N_PAD * D_SZ * 2);  // 102.5 MB
  float* lsq          = (float*)alloc((size_t)N_PAD * 4);
  float* embf         = (float*)alloc((size_t)B_SZ * D_SZ * 4);            // 4 MB
  unsigned short* emb = (unsigned short*)alloc((size_t)B_SZ * D_SZ * 2);
  float* esq          = (float*)alloc((size_t)B_SZ * 4);
  float* minpart      = (float*)alloc((size_t)NGRP * B_SZ * 4);            // 256 KB
  float* msep         = (float*)alloc(2048 * 4);
  float* msev         = (float*)alloc(256);
  (void)ws_size; (void)in_sizes; (void)n_in; (void)out_size;

  conv_mse_k<<<2048, 256, 0, stream>>>(x, y, xb, msep, (long)B_SZ * F_SZ / 8);
  dim3 tg(F_SZ / 64, D_SZ / 64);
  transpose_w_k<<<tg, 256, 0, stream>>>(W, Wt);
  conv_lookup_k<<<N_PAD / 4, 256, 0, stream>>>(lk, lb, lsq);
  zero_f32_k<<<1024, 256, 0, stream>>>(embf, (long)B_SZ * D_SZ / 4);

  // emb(f32) = xb @ Wt^T via split-K=4 atomicAdd
  gemm_a_sk<<<256, 256, 0, stream>>>(xb, Wt, embf);
  esq_conv_k<<<B_SZ / 4, 256, 0, stream>>>(embf, emb, esq);

  // persistent fused cdist-min (no atomics)
  gemm_min_k<<<256, 512, 0, stream>>>(emb, lb, esq, lsq, minpart);

  mse_final_k<<<1, 256, 0, stream>>>(msep, msev, 2048, 1.0f / ((float)B_SZ * (float)F_SZ));
  finalize_k<<<(B_SZ + 255) / 256, 256, 0, stream>>>(minpart, msev, out, B_SZ);
}

// Round 5
// 438.625 us; speedup vs baseline: 1.7872x; 1.0306x over previous
//
#include <hip/hip_runtime.h>
#include <math.h>

#define B_SZ   2048
#define F_SZ   12288
#define D_SZ   512
#define N_LK   100000
#define N_PAD  100096
#define NT2    782          // N_PAD / 128
#define NGRP   48           // persistent groups along nt (768 blocks = 16 mt x 48 grp)

typedef __attribute__((ext_vector_type(8))) short bf16x8;
typedef __attribute__((ext_vector_type(8))) unsigned short ushort8;
typedef __attribute__((ext_vector_type(4))) float f32x4;

__device__ __forceinline__ unsigned short f2bf(float f) {
  union { float f; unsigned u; } v; v.f = f;
  unsigned r = v.u + 0x7FFFu + ((v.u >> 16) & 1u);
  return (unsigned short)(r >> 16);
}
__device__ __forceinline__ float bf2f(unsigned short h) {
  union { unsigned u; float f; } v; v.u = ((unsigned)h) << 16;
  return v.f;
}

#define GLOAD16(gp, lp) __builtin_amdgcn_global_load_lds( \
    (__attribute__((address_space(1))) void*)(gp),        \
    (__attribute__((address_space(3))) void*)(lp), 16, 0, 0)

#define VMCNT(n) asm volatile("s_waitcnt vmcnt(" #n ")" ::: "memory")

// ---------------- fused x->bf16 conversion + mse partials ----------------

__global__ __launch_bounds__(256) void conv_mse_k(const float* __restrict__ x,
                                                  const float* __restrict__ y,
                                                  unsigned short* __restrict__ xb,
                                                  float* __restrict__ part, long n8) {
  long i = (long)blockIdx.x * 256 + threadIdx.x;
  long stride = (long)gridDim.x * 256;
  float s = 0.f;
  for (; i < n8; i += stride) {
    const float4* px = (const float4*)(x + i * 8);
    const float4* py = (const float4*)(y + i * 8);
    float4 a = px[0], b = px[1];
    float4 c = py[0], d = py[1];
    ushort8 o;
    o[0] = f2bf(a.x); o[1] = f2bf(a.y); o[2] = f2bf(a.z); o[3] = f2bf(a.w);
    o[4] = f2bf(b.x); o[5] = f2bf(b.y); o[6] = f2bf(b.z); o[7] = f2bf(b.w);
    *(ushort8*)(xb + i * 8) = o;
    float t0 = a.x - c.x, t1 = a.y - c.y, t2 = a.z - c.z, t3 = a.w - c.w;
    float t4 = b.x - d.x, t5 = b.y - d.y, t6 = b.z - d.z, t7 = b.w - d.w;
    s += t0 * t0 + t1 * t1 + t2 * t2 + t3 * t3;
    s += t4 * t4 + t5 * t5 + t6 * t6 + t7 * t7;
  }
#pragma unroll
  for (int off = 1; off < 64; off <<= 1) s += __shfl_xor(s, off);
  __shared__ float sm[4];
  if ((threadIdx.x & 63) == 0) sm[threadIdx.x >> 6] = s;
  __syncthreads();
  if (threadIdx.x == 0) part[blockIdx.x] = sm[0] + sm[1] + sm[2] + sm[3];
}

// W [F,D] f32 -> Wt [D,F] bf16
__global__ __launch_bounds__(256) void transpose_w_k(const float* __restrict__ W,
                                                     unsigned short* __restrict__ Wt) {
  __shared__ float tl[64][65];
  int t = threadIdx.x;
  int r0 = blockIdx.x * 64;  // F dim
  int c0 = blockIdx.y * 64;  // D dim
#pragma unroll
  for (int p = 0; p < 16; ++p) {
    int idx = p * 256 + t;
    int r = idx >> 6, c = idx & 63;
    tl[c][r] = W[(size_t)(r0 + r) * D_SZ + c0 + c];
  }
  __syncthreads();
#pragma unroll
  for (int p = 0; p < 2; ++p) {
    int chunk = p * 256 + t;
    int rr = chunk >> 3, cc = (chunk & 7) * 8;
    ushort8 o;
#pragma unroll
    for (int j = 0; j < 8; ++j) o[j] = f2bf(tl[rr][cc + j]);
    *(ushort8*)&Wt[(size_t)(c0 + rr) * F_SZ + r0 + cc] = o;
  }
}

// lookup f32 [N,512] -> bf16 rows (padded) + per-row sum of squares
__global__ __launch_bounds__(256) void conv_lookup_k(const float* __restrict__ lk,
                                                     unsigned short* __restrict__ lb,
                                                     float* __restrict__ lsq) {
  int n = blockIdx.x * 4 + (threadIdx.x >> 6);
  int t = threadIdx.x & 63;
  ushort8 o;
  float s = 0.f;
  if (n < N_LK) {
    const float4* row = (const float4*)(lk + (size_t)n * D_SZ);
    float4 a = row[t * 2], b = row[t * 2 + 1];
    float v[8] = {a.x, a.y, a.z, a.w, b.x, b.y, b.z, b.w};
#pragma unroll
    for (int j = 0; j < 8; ++j) {
      o[j] = f2bf(v[j]);
      float q = bf2f(o[j]);
      s += q * q;
    }
  } else {
#pragma unroll
    for (int j = 0; j < 8; ++j) o[j] = 0;
  }
  *(ushort8*)&lb[(size_t)n * D_SZ + t * 8] = o;
#pragma unroll
  for (int off = 1; off < 64; off <<= 1) s += __shfl_xor(s, off);
  if (t == 0) lsq[n] = (n < N_LK) ? s : 1e30f;
}

__global__ __launch_bounds__(256) void zero_f32_k(float* __restrict__ p, long n4) {
  long i = (long)blockIdx.x * 256 + threadIdx.x;
  long stride = (long)gridDim.x * 256;
  float4 z = {0.f, 0.f, 0.f, 0.f};
  for (; i < n4; i += stride) ((float4*)p)[i] = z;
}

// ---------------- GEMM-A split-K=12: embf(f32) += xb[128-tile] @ Wt^T[128-tile] ----------------
// grid 768 = mt(16) x dt(4) x ks(12); K-slice 1024 (32 steps), 3 blocks/CU.
// atomicAdd f32 epilogue (12 writers/address; output is hinge-clamped so rounding
// order is harmless).
__global__ __launch_bounds__(256) void gemm_a_sk(const unsigned short* __restrict__ A,
                                                 const unsigned short* __restrict__ Bm,
                                                 float* __restrict__ embf) {
  __shared__ unsigned short lsA[128 * 32];
  __shared__ unsigned short lsB[128 * 32];
  const int tid = threadIdx.x;
  const int bid = blockIdx.x;
  const int mt = bid & 15, dt = (bid >> 4) & 3, ks = bid >> 6;
  const int m0 = mt * 128, n0 = dt * 128;
  const int k0base = ks * 1024;
  const int l = tid & 63;
  const int w = tid >> 6;
  const int wr = (w >> 1) * 64, wc = (w & 1) * 64;
  const int g = l >> 4, lane16 = l & 15;

  const int srow = tid >> 2;
  const int scol = (tid & 3) * 8;
  const unsigned short* Ag0 = A + (size_t)(m0 + srow) * F_SZ + scol + k0base;
  const unsigned short* Ag1 = A + (size_t)(m0 + 64 + srow) * F_SZ + scol + k0base;
  const unsigned short* Bg0 = Bm + (size_t)(n0 + srow) * F_SZ + scol + k0base;
  const unsigned short* Bg1 = Bm + (size_t)(n0 + 64 + srow) * F_SZ + scol + k0base;
  unsigned short* la0 = &lsA[tid * 8];
  unsigned short* la1 = &lsA[2048 + tid * 8];
  unsigned short* lb0 = &lsB[tid * 8];
  unsigned short* lb1 = &lsB[2048 + tid * 8];

  int ar[4], br[4];
#pragma unroll
  for (int m = 0; m < 4; ++m) ar[m] = (wr + m * 16 + lane16) * 32 + g * 8;
#pragma unroll
  for (int n = 0; n < 4; ++n) br[n] = (wc + n * 16 + lane16) * 32 + g * 8;

  f32x4 acc[4][4] = {};

  for (int k0 = 0; k0 < 1024; k0 += 32) {
    GLOAD16(Ag0 + k0, la0);
    GLOAD16(Ag1 + k0, la1);
    GLOAD16(Bg0 + k0, lb0);
    GLOAD16(Bg1 + k0, lb1);
    __syncthreads();
    bf16x8 af[4], bfv[4];
#pragma unroll
    for (int m = 0; m < 4; ++m) af[m] = *(const bf16x8*)&lsA[ar[m]];
#pragma unroll
    for (int n = 0; n < 4; ++n) bfv[n] = *(const bf16x8*)&lsB[br[n]];
#pragma unroll
    for (int m = 0; m < 4; ++m)
#pragma unroll
      for (int n = 0; n < 4; ++n)
        acc[m][n] = __builtin_amdgcn_mfma_f32_16x16x32_bf16(af[m], bfv[n], acc[m][n], 0, 0, 0);
    __syncthreads();
  }
#pragma unroll
  for (int m = 0; m < 4; ++m)
#pragma unroll
    for (int n = 0; n < 4; ++n)
#pragma unroll
      for (int r = 0; r < 4; ++r) {
        int row = m0 + wr + m * 16 + g * 4 + r;
        int col = n0 + wc + n * 16 + lane16;
        atomicAdd(&embf[(size_t)row * D_SZ + col], acc[m][n][r]);
      }
}

// embf f32 -> emb bf16 + per-row esq (of the bf16-rounded values)
__global__ __launch_bounds__(256) void esq_conv_k(const float* __restrict__ embf,
                                                  unsigned short* __restrict__ emb,
                                                  float* __restrict__ esq) {
  int r = blockIdx.x * 4 + (threadIdx.x >> 6);
  int t = threadIdx.x & 63;
  const float4* row = (const float4*)(embf + (size_t)r * D_SZ);
  float4 a = row[t * 2], b = row[t * 2 + 1];
  float v[8] = {a.x, a.y, a.z, a.w, b.x, b.y, b.z, b.w};
  ushort8 o;
  float s = 0.f;
#pragma unroll
  for (int j = 0; j < 8; ++j) {
    o[j] = f2bf(v[j]);
    float q = bf2f(o[j]);
    s += q * q;
  }
  *(ushort8*)&emb[(size_t)r * D_SZ + t * 8] = o;
#pragma unroll
  for (int off = 1; off < 64; off <<= 1) s += __shfl_xor(s, off);
  if (t == 0) esq[r] = s;
}

// ---------------- GEMM-B: persistent fused cdist-min, 128x128, 3 blocks/CU ----------------
// grid 768 (3/CU), 256 threads (4 waves, 2x2; each wave 64x64 = acc[4][4], VGPR-light
// so 3 blocks co-reside -> cross-block overlap hides barrier/vmcnt stalls (m114/m97).
// mt = bid/48 (16 M-tiles of 128); grp = bid%48: the 16 blocks sharing a B-stream have
// bid = grp + 48*mt == grp (mod 8) -> SAME XCD (48%8==0) and co-start -> B fetched
// once per XCD into its L2. 2-deep LDS ring (2 x (A 8KB + B 8KB) = 32KB), counted
// vmcnt(4): tiles t+1,t+2 in flight, never drained mid-loop. Loads retire in order
// and all threads issue identical load sequences -> counted wait + barrier race-free.
// No atomics: per-row min folded in registers across nt, one store per (grp,row).
__global__ __launch_bounds__(256, 3) void gemm_min_k(
    const unsigned short* __restrict__ A,   // emb [2048][512] bf16
    const unsigned short* __restrict__ Bm,  // lb  [100096][512] bf16
    const float* __restrict__ esq, const float* __restrict__ lsq,
    float* __restrict__ minpart) {          // [NGRP][2048]
  __shared__ unsigned short lsA[2 * 4096];
  __shared__ unsigned short lsB[2 * 4096];

  const int tid = threadIdx.x;
  const int grp = blockIdx.x % NGRP;
  const int mt = blockIdx.x / NGRP;    // 0..15
  const int m0 = mt * 128;
  const int J = (NT2 - grp + NGRP - 1) / NGRP;  // 16 or 17 nt-tiles
  const int T = J * 16;                         // total K-steps (K=512/BK=32 per tile)

  const int l = tid & 63;
  const int w = tid >> 6;
  const int wr = (w >> 1) * 64, wc = (w & 1) * 64;
  const int g = l >> 4, lane16 = l & 15;

  // staging: linear LDS dest; global source column slot pre-swizzled so ds_read's
  // slot' = slot ^ ((row>>1)&3) finds the right data (both-sides-or-neither rule).
  const int srow = tid >> 2;                       // 0..63
  const int sslot = (tid & 3) ^ ((tid >> 3) & 3);  // row parity block invariant mod 4
  const unsigned short* Ag0 = A + (size_t)(m0 + srow) * D_SZ + sslot * 8;
  const unsigned short* Ag1 = A + (size_t)(m0 + 64 + srow) * D_SZ + sslot * 8;
  const unsigned short* Bgs = Bm + (size_t)srow * D_SZ + sslot * 8;

  int ar[4], br[4];
#pragma unroll
  for (int m = 0; m < 4; ++m) {
    int row = wr + m * 16 + lane16;
    ar[m] = row * 32 + ((g ^ ((row >> 1) & 3)) * 8);
  }
#pragma unroll
  for (int n = 0; n < 4; ++n) {
    int row = wc + n * 16 + lane16;
    br[n] = row * 32 + ((g ^ ((row >> 1) & 3)) * 8);
  }

  f32x4 acc[4][4] = {};
  float rmin[4][4];
#pragma unroll
  for (int m = 0; m < 4; ++m)
#pragma unroll
    for (int r = 0; r < 4; ++r) rmin[m][r] = 3.0e38f;

  auto stage = [&](int s) {
    const int kt = (s & 15) * 32;
    const int b = s & 1;
    const size_t nrow = (size_t)(grp + NGRP * (s >> 4)) * 128 * D_SZ;
    GLOAD16(Ag0 + kt, &lsA[b * 4096 + tid * 8]);
    GLOAD16(Ag1 + kt, &lsA[b * 4096 + 2048 + tid * 8]);
    GLOAD16(Bgs + nrow + kt, &lsB[b * 4096 + tid * 8]);
    GLOAD16(Bgs + nrow + (size_t)64 * D_SZ + kt, &lsB[b * 4096 + 2048 + tid * 8]);
  };

  // prologue: tiles 0,1 in flight; retire tile 0
  stage(0); stage(1);
  VMCNT(4);
  __builtin_amdgcn_s_barrier();

  for (int t = 0; t < T; ++t) {
    const int b = t & 1;
    const unsigned short* pA = &lsA[b * 4096];
    const unsigned short* pB = &lsB[b * 4096];
    bf16x8 af[4], bfv[4];
#pragma unroll
    for (int n = 0; n < 4; ++n) bfv[n] = *(const bf16x8*)&pB[br[n]];
#pragma unroll
    for (int m = 0; m < 4; ++m) af[m] = *(const bf16x8*)&pA[ar[m]];
    asm volatile("s_waitcnt lgkmcnt(0)" ::: "memory");
    __builtin_amdgcn_sched_barrier(0);
    __builtin_amdgcn_s_barrier();            // all waves' reads done -> buf b reusable
    if (t + 2 < T) stage(t + 2);             // uniform branch
    __builtin_amdgcn_s_setprio(1);
#pragma unroll
    for (int m = 0; m < 4; ++m)
#pragma unroll
      for (int n = 0; n < 4; ++n)
        acc[m][n] = __builtin_amdgcn_mfma_f32_16x16x32_bf16(af[m], bfv[n], acc[m][n], 0, 0, 0);
    __builtin_amdgcn_s_setprio(0);
    if ((t & 15) == 15) {                    // nt-tile boundary: fold min, reset acc
      const int j = t >> 4;
      const int n0s = (grp + NGRP * j) * 128;
      float lsql[4];
#pragma unroll
      for (int n = 0; n < 4; ++n) lsql[n] = lsq[n0s + wc + n * 16 + lane16];
#pragma unroll
      for (int m = 0; m < 4; ++m)
#pragma unroll
        for (int r = 0; r < 4; ++r) {
          float v = fminf(fminf(lsql[0] - 2.0f * acc[m][0][r], lsql[1] - 2.0f * acc[m][1][r]),
                          fminf(lsql[2] - 2.0f * acc[m][2][r], lsql[3] - 2.0f * acc[m][3][r]));
          rmin[m][r] = fminf(rmin[m][r], v);
        }
#pragma unroll
      for (int m = 0; m < 4; ++m)
#pragma unroll
        for (int n = 0; n < 4; ++n) acc[m][n] = f32x4{0.f, 0.f, 0.f, 0.f};
    }
    if (t + 2 < T) { VMCNT(4); }             // retire tile t+1; t+2 in flight
    else if (t + 1 < T) { VMCNT(0); }        // retire final tile
    __builtin_amdgcn_s_barrier();            // publish tile t+1
  }

  // writeout: reduce rmin over the 16-lane col group, one store per (grp,row)
#pragma unroll
  for (int m = 0; m < 4; ++m)
#pragma unroll
    for (int r = 0; r < 4; ++r) {
      float best = rmin[m][r];
#pragma unroll
      for (int off = 1; off < 16; off <<= 1) best = fminf(best, __shfl_xor(best, off));
      if (lane16 == 0) {
        int row = m0 + wr + m * 16 + g * 4 + r;
        minpart[grp * B_SZ + row] = fmaxf(esq[row] + best, 0.0f);
      }
    }
}

// ---------------- final reductions ----------------

__global__ __launch_bounds__(256) void mse_final_k(const float* __restrict__ part,
                                                   float* __restrict__ msev,
                                                   int nparts, float inv_n) {
  float s = 0.f;
  for (int i = threadIdx.x; i < nparts; i += 256) s += part[i];
#pragma unroll
  for (int off = 1; off < 64; off <<= 1) s += __shfl_xor(s, off);
  __shared__ float sm[4];
  if ((threadIdx.x & 63) == 0) sm[threadIdx.x >> 6] = s;
  __syncthreads();
  if (threadIdx.x == 0) msev[0] = (sm[0] + sm[1] + sm[2] + sm[3]) * inv_n;
}

__global__ void finalize_k(const float* __restrict__ minpart,
                           const float* __restrict__ msev,
                           float* __restrict__ out, int n) {
  int i = blockIdx.x * blockDim.x + threadIdx.x;
  if (i < n) {
    float m = 3.0e38f;
#pragma unroll 8
    for (int gp = 0; gp < NGRP; ++gp) m = fminf(m, minpart[gp * B_SZ + i]);
    out[i] = msev[0] + fminf(50.0f - sqrtf(m), 0.0f) * 5.0f;
  }
}

// ---------------- launch ----------------

extern "C" void kernel_launch(void* const* d_in, const int* in_sizes, int n_in,
                              void* d_out, int out_size, void* d_ws, size_t ws_size,
                              hipStream_t stream) {
  const float* x  = (const float*)d_in[0];
  const float* y  = (const float*)d_in[1];
  const float* W  = (const float*)d_in[2];
  const float* lk = (const float*)d_in[3];
  float* out = (float*)d_out;

  char* ws = (char*)d_ws;
  size_t off = 0;
  auto alloc = [&](size_t bytes) -> void* {
    void* p = ws + off;
    off = (off + bytes + 255) & ~(size_t)255;
    return p;
  };
  unsigned short* xb  = (unsigned short*)alloc((size_t)B_SZ * F_SZ * 2);   // 50.3 MB
  unsigned short* Wt  = (unsigned short*)alloc((size_t)D_SZ * F_SZ * 2);   // 12.6 MB
  unsigned short* lb  = (unsigned short*)alloc((size_t)N_PAD * D_SZ * 2);  // 102.5 MB
  float* lsq          = (float*)alloc((size_t)N_PAD * 4);
  float* embf         = (float*)alloc((size_t)B_SZ * D_SZ * 4);            // 4 MB
  unsigned short* emb = (unsigned short*)alloc((size_t)B_SZ * D_SZ * 2);
  float* esq          = (float*)alloc((size_t)B_SZ * 4);
  float* minpart      = (float*)alloc((size_t)NGRP * B_SZ * 4);            // 384 KB
  float* msep         = (float*)alloc(2048 * 4);
  float* msev         = (float*)alloc(256);
  (void)ws_size; (void)in_sizes; (void)n_in; (void)out_size;

  conv_mse_k<<<2048, 256, 0, stream>>>(x, y, xb, msep, (long)B_SZ * F_SZ / 8);
  dim3 tg(F_SZ / 64, D_SZ / 64);
  transpose_w_k<<<tg, 256, 0, stream>>>(W, Wt);
  conv_lookup_k<<<N_PAD / 4, 256, 0, stream>>>(lk, lb, lsq);
  zero_f32_k<<<1024, 256, 0, stream>>>(embf, (long)B_SZ * D_SZ / 4);

  // emb(f32) = xb @ Wt^T via split-K=12 atomicAdd (768 blocks, 3/CU)
  gemm_a_sk<<<768, 256, 0, stream>>>(xb, Wt, embf);
  esq_conv_k<<<B_SZ / 4, 256, 0, stream>>>(embf, emb, esq);

  // persistent fused cdist-min (no atomics), 768 blocks, 3/CU
  gemm_min_k<<<768, 256, 0, stream>>>(emb, lb, esq, lsq, minpart);

  mse_final_k<<<1, 256, 0, stream>>>(msep, msev, 2048, 1.0f / ((float)B_SZ * (float)F_SZ));
  finalize_k<<<(B_SZ + 255) / 256, 256, 0, stream>>>(minpart, msev, out, B_SZ);
}